// Round 3
// baseline (194.840 us; speedup 1.0000x reference)
//
#include <hip/hip_runtime.h>
#include <hip/hip_bf16.h>

typedef __attribute__((ext_vector_type(4))) float f32x4;
typedef __attribute__((ext_vector_type(8))) short bf16x8;

// fp32 -> bf16 bits, round-to-nearest-even
__device__ __forceinline__ unsigned short f2bf(float f) {
  unsigned int u = __builtin_bit_cast(unsigned int, f);
  u += 0x7FFFu + ((u >> 16) & 1u);
  return (unsigned short)(u >> 16);
}

// async 16B global -> LDS (wave-uniform LDS base + lane*16 hardware scatter)
__device__ __forceinline__ void async_ld16(const void* g, void* l) {
  __builtin_amdgcn_global_load_lds(
      (__attribute__((address_space(1))) void*)g,
      (__attribute__((address_space(3))) void*)l, 16, 0, 0);
}

// ---------------------------------------------------------------------------
// Weight packing (one launch): fragment-order bf16, 16B/lane coalesced loads.
// Apack[chunk][t][lane][j] = Acat[chunk*32 + (lane>>4)*8 + j][t*16 + (lane&15)]
// Bpack[kc][nt][lane][j]   = SCALE * Bcat[kc*32 + (lane>>4)*8 + j][nt*16 + (lane&15)]
// ---------------------------------------------------------------------------
__global__ __launch_bounds__(256) void pack_AB(
    const float* __restrict__ Af, const float* __restrict__ Am,
    const float* __restrict__ As, const float* __restrict__ Bf,
    const float* __restrict__ Bm, const float* __restrict__ Bs,
    short* __restrict__ Apack, short* __restrict__ Bpack)
{
  unsigned idx = blockIdx.x * 256u + threadIdx.x;     // < 786432
  if (idx < 393216u) {
    unsigned j = idx & 7u, lane = (idx >> 3) & 63u, rest = idx >> 9;
    unsigned t = rest % 6u, chunk = rest / 6u;
    unsigned k = chunk * 32u + ((lane >> 4) << 3) + j;
    unsigned c = t * 16u + (lane & 15u);
    float v;
    if (c < 32u)      v = Af[k * 32u + c];
    else if (c < 64u) v = Am[k * 32u + (c - 32u)];
    else              v = As[k * 32u + (c - 64u)];
    Apack[idx] = (short)f2bf(v);
  } else {
    unsigned i2 = idx - 393216u;
    unsigned j = i2 & 7u, lane = (i2 >> 3) & 63u, rest = i2 >> 9;
    unsigned nt = rest & 255u, kc = rest >> 8;
    unsigned k = kc * 32u + ((lane >> 4) << 3) + j;
    unsigned n = nt * 16u + (lane & 15u);
    float v;
    if (k < 32u)      v = Bf[k * 4096u + n];
    else if (k < 64u) v = Bm[(k - 32u) * 4096u + n];
    else              v = Bs[(k - 64u) * 4096u + n];
    Bpack[i2] = (short)f2bf(v * 0.03125f);            // fold SCALE = 1/32
  }
}

// ---------------------------------------------------------------------------
// Fused LoRA. 512 blocks x 512 threads (8 waves), 32 rows/block.
// Phase 1: double-buffered global_load_lds staging of x (fragment-ordered,
// 32 KB per K-step of 256), waves (mt,nh,kp) accumulate h-partials via MFMA.
// Reduce partials in reused LDS -> bf16 hfrag. Phase 2: out = h @ Bpack
// (weights L2-resident). No hpart HBM round-trip.
// ---------------------------------------------------------------------------
__global__ __launch_bounds__(512, 4) void lora_fused(
    const float* __restrict__ x, const short* __restrict__ Apack,
    const short* __restrict__ Bpack, float* __restrict__ out)
{
  const int rb  = blockIdx.x;
  const int tid = threadIdx.x;
  const int w = tid >> 6, l = tid & 63;
  const int lm = l & 15, lk = l >> 4;
  const int mt = w & 1;          // M-tile (16 rows)
  const int nh = (w >> 1) & 1;   // phase-1 N-half (48 cols)
  const int kp = w >> 2;         // phase-1 ks-parity (4 ksubs each)

  __shared__ __align__(16) float xs[2][8192];        // 64 KiB staging
  __shared__ __align__(16) short hfrag[2][3][64][8]; // 6 KiB

  const int rowbase = rb * 32;

  // chunk c = 0..31 -> (cmt=c>>4, cks=(c>>1)&7, h2=c&1); LDS slot = c*1KiB,
  // lane slot l*16B holds x[row=rowbase+cmt*16+(l&15)][s*256+cks*32+(l>>4)*8+h2*4 ..+4]
  auto stage = [&](int s, float* bufp) {
#pragma unroll
    for (int i = 0; i < 4; ++i) {
      int c = w * 4 + i;
      int cmt = c >> 4, cks = (c >> 1) & 7, h2 = c & 1;
      const float* gp = x + (size_t)(rowbase + cmt * 16 + lm) * 4096
                          + s * 256 + cks * 32 + lk * 8 + h2 * 4;
      async_ld16(gp, bufp + c * 256);
    }
  };

  f32x4 acc[3];
  acc[0] = acc[1] = acc[2] = (f32x4){0.f, 0.f, 0.f, 0.f};

  stage(0, xs[0]);
  for (int s = 0; s < 16; ++s) {
    float* buf = xs[s & 1];
    if (s < 15) stage(s + 1, xs[(s & 1) ^ 1]);
    __syncthreads();                        // staging of buf landed (per-wave vmcnt drain)
#pragma unroll
    for (int jk = 0; jk < 4; ++jk) {
      int ks = kp * 4 + jk;
      f32x4 a0 = *(const f32x4*)(buf + (mt * 16 + ks * 2 + 0) * 256 + l * 4);
      f32x4 a1 = *(const f32x4*)(buf + (mt * 16 + ks * 2 + 1) * 256 + l * 4);
      bf16x8 xf;
      xf[0] = (short)f2bf(a0[0]); xf[1] = (short)f2bf(a0[1]);
      xf[2] = (short)f2bf(a0[2]); xf[3] = (short)f2bf(a0[3]);
      xf[4] = (short)f2bf(a1[0]); xf[5] = (short)f2bf(a1[1]);
      xf[6] = (short)f2bf(a1[2]); xf[7] = (short)f2bf(a1[3]);
      int kchunk = s * 8 + ks;
#pragma unroll
      for (int tt = 0; tt < 3; ++tt) {
        bf16x8 bv = *(const bf16x8*)(Apack + ((size_t)kchunk * 6 + nh * 3 + tt) * 512 + l * 8);
        acc[tt] = __builtin_amdgcn_mfma_f32_16x16x32_bf16(xf, bv, acc[tt], 0, 0, 0);
      }
    }
    __syncthreads();                        // all reads of buf done before restage
  }

  // ---- reduce K-partials (reuse xs as hp[(mt*2+kp)][16][104]) ----
  float* hp = xs[0];
#pragma unroll
  for (int tt = 0; tt < 3; ++tt)
#pragma unroll
    for (int q = 0; q < 4; ++q)
      hp[(mt * 2 + kp) * 1664 + (lk * 4 + q) * 104 + (nh * 3 + tt) * 16 + lm] = acc[tt][q];
  __syncthreads();

  if (tid < 384) {
    int r5 = tid / 12, cg = tid % 12;       // row 0..31, col-group of 8
    int gmt = r5 >> 4, ri = r5 & 15;
    const float* p0 = hp + (gmt * 2 + 0) * 1664 + ri * 104 + cg * 8;
    const float* p1 = hp + (gmt * 2 + 1) * 1664 + ri * 104 + cg * 8;
    f32x4 s0 = *(const f32x4*)p0 + *(const f32x4*)p1;
    f32x4 s1 = *(const f32x4*)(p0 + 4) + *(const f32x4*)(p1 + 4);
    bf16x8 o;
    o[0] = (short)f2bf(s0[0]); o[1] = (short)f2bf(s0[1]);
    o[2] = (short)f2bf(s0[2]); o[3] = (short)f2bf(s0[3]);
    o[4] = (short)f2bf(s1[0]); o[5] = (short)f2bf(s1[1]);
    o[6] = (short)f2bf(s1[2]); o[7] = (short)f2bf(s1[3]);
    *(bf16x8*)&hfrag[gmt][cg >> 2][(cg & 3) * 16 + ri][0] = o;
  }
  __syncthreads();

  // ---- phase 2: out tile = h @ Bpack, wave (mt, ch) = 16 rows x 1024 cols --
  {
    const int ch = w >> 1;                  // col-quarter 0..3
    bf16x8 hf[3];
#pragma unroll
    for (int kc = 0; kc < 3; ++kc)
      hf[kc] = *(const bf16x8*)&hfrag[mt][kc][l][0];   // lane-linear, conflict-free

    const short* bp = Bpack + (size_t)l * 8;
    for (int cc = 0; cc < 4; ++cc) {
      f32x4 acc2[16];
#pragma unroll
      for (int t = 0; t < 16; ++t) acc2[t] = (f32x4){0.f, 0.f, 0.f, 0.f};
      const int ntbase = ch * 64 + cc * 16;
#pragma unroll
      for (int kc = 0; kc < 3; ++kc)
#pragma unroll
        for (int t = 0; t < 16; ++t) {
          bf16x8 bv = *(const bf16x8*)(bp + (size_t)(kc * 256 + ntbase + t) * 512);
          acc2[t] = __builtin_amdgcn_mfma_f32_16x16x32_bf16(hf[kc], bv, acc2[t], 0, 0, 0);
        }
      float* op = out + ((size_t)rowbase + mt * 16 + lk * 4) * 4096 + ch * 1024 + cc * 256 + lm;
#pragma unroll
      for (int t = 0; t < 16; ++t)
#pragma unroll
        for (int q = 0; q < 4; ++q)
          op[(size_t)q * 4096 + t * 16] = acc2[t][q];
    }
  }
}

extern "C" void kernel_launch(void* const* d_in, const int* in_sizes, int n_in,
                              void* d_out, int out_size, void* d_ws, size_t ws_size,
                              hipStream_t stream) {
  const float* x  = (const float*)d_in[0];
  const float* Af = (const float*)d_in[1];
  const float* Bf = (const float*)d_in[2];
  const float* Am = (const float*)d_in[3];
  const float* Bm = (const float*)d_in[4];
  const float* As = (const float*)d_in[5];
  const float* Bs = (const float*)d_in[6];
  float* out = (float*)d_out;

  char* ws = (char*)d_ws;
  short* Apack = (short*)ws;                  // 786432 B
  short* Bpack = (short*)(ws + 786432);       // 786432 B

  hipLaunchKernelGGL(pack_AB, dim3(3072), dim3(256), 0, stream,
                     Af, Am, As, Bf, Bm, Bs, Apack, Bpack);
  hipLaunchKernelGGL(lora_fused, dim3(512), dim3(512), 0, stream, x, Apack, Bpack, out);
}

// Round 5
// 179.449 us; speedup vs baseline: 1.0858x; 1.0858x over previous
//
#include <hip/hip_runtime.h>
#include <hip/hip_bf16.h>

typedef __attribute__((ext_vector_type(4))) float f32x4;
typedef __attribute__((ext_vector_type(8))) short bf16x8;

// fp32 -> bf16 bits, round-to-nearest-even
__device__ __forceinline__ unsigned short f2bf(float f) {
  unsigned int u = __builtin_bit_cast(unsigned int, f);
  u += 0x7FFFu + ((u >> 16) & 1u);
  return (unsigned short)(u >> 16);
}

// ---------------------------------------------------------------------------
// Weight packing (one launch): fragment-order bf16, 16B/lane coalesced loads.
// Apack[chunk][t][lane][j] = Acat[chunk*32 + (lane>>4)*8 + j][t*16 + (lane&15)]
// Bpack[kc][nt][lane][j]   = SCALE * Bcat[kc*32 + (lane>>4)*8 + j][nt*16 + (lane&15)]
// ---------------------------------------------------------------------------
__global__ __launch_bounds__(256) void pack_AB(
    const float* __restrict__ Af, const float* __restrict__ Am,
    const float* __restrict__ As, const float* __restrict__ Bf,
    const float* __restrict__ Bm, const float* __restrict__ Bs,
    short* __restrict__ Apack, short* __restrict__ Bpack)
{
  unsigned idx = blockIdx.x * 256u + threadIdx.x;     // < 786432
  if (idx < 393216u) {
    unsigned j = idx & 7u, lane = (idx >> 3) & 63u, rest = idx >> 9;
    unsigned t = rest % 6u, chunk = rest / 6u;
    unsigned k = chunk * 32u + ((lane >> 4) << 3) + j;
    unsigned c = t * 16u + (lane & 15u);
    float v;
    if (c < 32u)      v = Af[k * 32u + c];
    else if (c < 64u) v = Am[k * 32u + (c - 32u)];
    else              v = As[k * 32u + (c - 64u)];
    Apack[idx] = (short)f2bf(v);
  } else {
    unsigned i2 = idx - 393216u;
    unsigned j = i2 & 7u, lane = (i2 >> 3) & 63u, rest = i2 >> 9;
    unsigned nt = rest & 255u, kc = rest >> 8;
    unsigned k = kc * 32u + ((lane >> 4) << 3) + j;
    unsigned n = nt * 16u + (lane & 15u);
    float v;
    if (k < 32u)      v = Bf[k * 4096u + n];
    else if (k < 64u) v = Bm[(k - 32u) * 4096u + n];
    else              v = Bs[(k - 64u) * 4096u + n];
    Bpack[i2] = (short)f2bf(v * 0.03125f);            // fold SCALE = 1/32
  }
}

// ---------------------------------------------------------------------------
// Fused LoRA. 512 blocks x 256 threads (4 waves), 32 rows/block.
// Phase 1: wave (mt, kh) = 16 rows x K-half (2048) x all 96 h-cols. Per chunk
// one asm block of 8 homogeneous global_load_dwordx4 (2 x + 6 A) into E/O
// register sets; counted s_waitcnt vmcnt(8); no LDS in the loop. K-halves
// reduced via fp32 LDS. Phase 2: out = h @ Bpack (weights L2-resident).
// ---------------------------------------------------------------------------
__global__ __launch_bounds__(256, 4) void lora_fused(
    const float* __restrict__ x, const short* __restrict__ Apack,
    const short* __restrict__ Bpack, float* __restrict__ out)
{
  const int rb  = blockIdx.x;
  const int tid = threadIdx.x;
  const int w = tid >> 6, l = tid & 63;
  const int lm = l & 15, lk = l >> 4;
  const int mt = w & 1;          // row tile (16 rows)
  const int kh = w >> 1;         // K half: chunks kh*64 .. +64
  const int rowbase = rb * 32;

  __shared__ float hp[2][32][100];   // [kh][row][96 padded] fp32 partials

  const float* xp = x + (size_t)(rowbase + mt * 16 + lm) * 4096
                      + kh * 2048 + lk * 8;
  const short* ap = Apack + (size_t)(kh * 64) * 3072 + (size_t)l * 8;

  f32x4 xE0, xE1, xO0, xO1;
  bf16x8 aE0, aE1, aE2, aE3, aE4, aE5;
  bf16x8 aO0, aO1, aO2, aO3, aO4, aO5;

  // 8 homogeneous register loads; A tiles at +0..+3KB from ap, +4..+5KB via ap2
#define LOAD8(X0, X1, A0, A1, A2, A3, A4, A5, XP, AP) do {              \
    const short* ap2_ = (AP) + 2048;                                    \
    asm volatile(                                                       \
      "global_load_dwordx4 %0, %8, off\n\t"                             \
      "global_load_dwordx4 %1, %8, off offset:16\n\t"                   \
      "global_load_dwordx4 %2, %9, off\n\t"                             \
      "global_load_dwordx4 %3, %9, off offset:1024\n\t"                 \
      "global_load_dwordx4 %4, %9, off offset:2048\n\t"                 \
      "global_load_dwordx4 %5, %9, off offset:3072\n\t"                 \
      "global_load_dwordx4 %6, %10, off\n\t"                            \
      "global_load_dwordx4 %7, %10, off offset:1024"                    \
      : "=&v"(X0), "=&v"(X1), "=&v"(A0), "=&v"(A1), "=&v"(A2),          \
        "=&v"(A3), "=&v"(A4), "=&v"(A5)                                 \
      : "v"(XP), "v"(AP), "v"(ap2_)                                     \
      : "memory");                                                      \
  } while (0)

#define CONSUME(X0, X1, A0, A1, A2, A3, A4, A5) do {                    \
    bf16x8 xf_;                                                         \
    xf_[0] = (short)f2bf(X0[0]); xf_[1] = (short)f2bf(X0[1]);           \
    xf_[2] = (short)f2bf(X0[2]); xf_[3] = (short)f2bf(X0[3]);           \
    xf_[4] = (short)f2bf(X1[0]); xf_[5] = (short)f2bf(X1[1]);           \
    xf_[6] = (short)f2bf(X1[2]); xf_[7] = (short)f2bf(X1[3]);           \
    acc0 = __builtin_amdgcn_mfma_f32_16x16x32_bf16(xf_, A0, acc0, 0, 0, 0); \
    acc1 = __builtin_amdgcn_mfma_f32_16x16x32_bf16(xf_, A1, acc1, 0, 0, 0); \
    acc2 = __builtin_amdgcn_mfma_f32_16x16x32_bf16(xf_, A2, acc2, 0, 0, 0); \
    acc3 = __builtin_amdgcn_mfma_f32_16x16x32_bf16(xf_, A3, acc3, 0, 0, 0); \
    acc4 = __builtin_amdgcn_mfma_f32_16x16x32_bf16(xf_, A4, acc4, 0, 0, 0); \
    acc5 = __builtin_amdgcn_mfma_f32_16x16x32_bf16(xf_, A5, acc5, 0, 0, 0); \
  } while (0)

  f32x4 acc0 = {0.f, 0.f, 0.f, 0.f};
  f32x4 acc1 = acc0, acc2 = acc0, acc3 = acc0, acc4 = acc0, acc5 = acc0;

  // Prologue: chunks 0 (E), 1 (O). FIFO = 16 outstanding.
  LOAD8(xE0, xE1, aE0, aE1, aE2, aE3, aE4, aE5, xp, ap); xp += 32; ap += 3072;
  LOAD8(xO0, xO1, aO0, aO1, aO2, aO3, aO4, aO5, xp, ap); xp += 32; ap += 3072;

  // Iter c: wait(8) -> chunk c (oldest 8) landed; consume; reload set.
#pragma unroll 1
  for (int c = 0; c < 62; c += 2) {
    asm volatile("s_waitcnt vmcnt(8)" ::: "memory");
    __builtin_amdgcn_sched_barrier(0);
    CONSUME(xE0, xE1, aE0, aE1, aE2, aE3, aE4, aE5);
    LOAD8(xE0, xE1, aE0, aE1, aE2, aE3, aE4, aE5, xp, ap); xp += 32; ap += 3072;
    asm volatile("s_waitcnt vmcnt(8)" ::: "memory");
    __builtin_amdgcn_sched_barrier(0);
    CONSUME(xO0, xO1, aO0, aO1, aO2, aO3, aO4, aO5);
    LOAD8(xO0, xO1, aO0, aO1, aO2, aO3, aO4, aO5, xp, ap); xp += 32; ap += 3072;
  }
  // Peel chunks 62, 63
  asm volatile("s_waitcnt vmcnt(8)" ::: "memory");
  __builtin_amdgcn_sched_barrier(0);
  CONSUME(xE0, xE1, aE0, aE1, aE2, aE3, aE4, aE5);
  asm volatile("s_waitcnt vmcnt(0)" ::: "memory");
  __builtin_amdgcn_sched_barrier(0);
  CONSUME(xO0, xO1, aO0, aO1, aO2, aO3, aO4, aO5);

  // D layout (m89): row = lk*4+q, col = lm
  {
    f32x4 accs[6] = {acc0, acc1, acc2, acc3, acc4, acc5};
#pragma unroll
    for (int t = 0; t < 6; ++t)
#pragma unroll
      for (int q = 0; q < 4; ++q)
        hp[kh][mt * 16 + lk * 4 + q][t * 16 + lm] = accs[t][q];
  }
  __syncthreads();

  // ---- phase 2: out tile = h @ Bpack, wave (mt2, nh2) = 16 rows x 2048 cols
  {
    const int mt2 = w & 1, nh2 = w >> 1;
    bf16x8 hf[3];
#pragma unroll
    for (int kc = 0; kc < 3; ++kc) {
      f32x4 h0 = *(const f32x4*)&hp[0][mt2 * 16 + lm][kc * 32 + lk * 8]
               + *(const f32x4*)&hp[1][mt2 * 16 + lm][kc * 32 + lk * 8];
      f32x4 h1 = *(const f32x4*)&hp[0][mt2 * 16 + lm][kc * 32 + lk * 8 + 4]
               + *(const f32x4*)&hp[1][mt2 * 16 + lm][kc * 32 + lk * 8 + 4];
      bf16x8 o;
      o[0] = (short)f2bf(h0[0]); o[1] = (short)f2bf(h0[1]);
      o[2] = (short)f2bf(h0[2]); o[3] = (short)f2bf(h0[3]);
      o[4] = (short)f2bf(h1[0]); o[5] = (short)f2bf(h1[1]);
      o[6] = (short)f2bf(h1[2]); o[7] = (short)f2bf(h1[3]);
      hf[kc] = o;
    }

    const short* bp = Bpack + (size_t)l * 8;
#pragma unroll 1
    for (int cc = 0; cc < 8; ++cc) {
      f32x4 a2[16];
#pragma unroll
      for (int t = 0; t < 16; ++t) a2[t] = (f32x4){0.f, 0.f, 0.f, 0.f};
      const int ntbase = nh2 * 128 + cc * 16;
#pragma unroll
      for (int kc = 0; kc < 3; ++kc)
#pragma unroll
        for (int t = 0; t < 16; ++t) {
          bf16x8 bv = *(const bf16x8*)(bp + (size_t)(kc * 256 + ntbase + t) * 512);
          a2[t] = __builtin_amdgcn_mfma_f32_16x16x32_bf16(hf[kc], bv, a2[t], 0, 0, 0);
        }
      float* op = out + ((size_t)rowbase + mt2 * 16 + lk * 4) * 4096
                      + nh2 * 2048 + cc * 256 + lm;
#pragma unroll
      for (int t = 0; t < 16; ++t)
#pragma unroll
        for (int q = 0; q < 4; ++q)
          op[(size_t)q * 4096 + t * 16] = a2[t][q];
    }
  }
}

extern "C" void kernel_launch(void* const* d_in, const int* in_sizes, int n_in,
                              void* d_out, int out_size, void* d_ws, size_t ws_size,
                              hipStream_t stream) {
  const float* x  = (const float*)d_in[0];
  const float* Af = (const float*)d_in[1];
  const float* Bf = (const float*)d_in[2];
  const float* Am = (const float*)d_in[3];
  const float* Bm = (const float*)d_in[4];
  const float* As = (const float*)d_in[5];
  const float* Bs = (const float*)d_in[6];
  float* out = (float*)d_out;

  char* ws = (char*)d_ws;
  short* Apack = (short*)ws;                  // 786432 B
  short* Bpack = (short*)(ws + 786432);       // 786432 B

  hipLaunchKernelGGL(pack_AB, dim3(3072), dim3(256), 0, stream,
                     Af, Am, As, Bf, Bm, Bs, Apack, Bpack);
  hipLaunchKernelGGL(lora_fused, dim3(512), dim3(256), 0, stream, x, Apack, Bpack, out);
}

// Round 6
// 173.302 us; speedup vs baseline: 1.1243x; 1.0355x over previous
//
#include <hip/hip_runtime.h>
#include <hip/hip_bf16.h>

typedef __attribute__((ext_vector_type(4))) float f32x4;
typedef __attribute__((ext_vector_type(8))) short bf16x8;

// fp32 -> bf16 bits, round-to-nearest-even
__device__ __forceinline__ unsigned short f2bf(float f) {
  unsigned int u = __builtin_bit_cast(unsigned int, f);
  u += 0x7FFFu + ((u >> 16) & 1u);
  return (unsigned short)(u >> 16);
}

// async 16B global -> LDS (wave-uniform LDS base + lane*16 hardware layout)
__device__ __forceinline__ void async_ld16(const void* g, void* l) {
  __builtin_amdgcn_global_load_lds(
      (__attribute__((address_space(1))) void*)g,
      (__attribute__((address_space(3))) void*)l, 16, 0, 0);
}

// ---------------------------------------------------------------------------
// Weight packing: fragment-order bf16 (identical layout serves A-op and B-op).
// Apack[chunk][t][lane][j] = Acat[chunk*32 + (lane>>4)*8 + j][t*16 + (lane&15)]
// Bpack[kc][nt][lane][j]   = SCALE * Bcat[kc*32 + (lane>>4)*8 + j][nt*16 + (lane&15)]
// ---------------------------------------------------------------------------
__global__ __launch_bounds__(256) void pack_AB(
    const float* __restrict__ Af, const float* __restrict__ Am,
    const float* __restrict__ As, const float* __restrict__ Bf,
    const float* __restrict__ Bm, const float* __restrict__ Bs,
    short* __restrict__ Apack, short* __restrict__ Bpack)
{
  unsigned idx = blockIdx.x * 256u + threadIdx.x;     // < 786432
  if (idx < 393216u) {
    unsigned j = idx & 7u, lane = (idx >> 3) & 63u, rest = idx >> 9;
    unsigned t = rest % 6u, chunk = rest / 6u;
    unsigned k = chunk * 32u + ((lane >> 4) << 3) + j;
    unsigned c = t * 16u + (lane & 15u);
    float v;
    if (c < 32u)      v = Af[k * 32u + c];
    else if (c < 64u) v = Am[k * 32u + (c - 32u)];
    else              v = As[k * 32u + (c - 64u)];
    Apack[idx] = (short)f2bf(v);
  } else {
    unsigned i2 = idx - 393216u;
    unsigned j = i2 & 7u, lane = (i2 >> 3) & 63u, rest = i2 >> 9;
    unsigned nt = rest & 255u, kc = rest >> 8;
    unsigned k = kc * 32u + ((lane >> 4) << 3) + j;
    unsigned n = nt * 16u + (lane & 15u);
    float v;
    if (k < 32u)      v = Bf[k * 4096u + n];
    else if (k < 64u) v = Bm[(k - 32u) * 4096u + n];
    else              v = Bs[(k - 64u) * 4096u + n];
    Bpack[i2] = (short)f2bf(v * 0.03125f);            // fold SCALE = 1/32
  }
}

// ---------------------------------------------------------------------------
// Fused LoRA. 1024 blocks x 256 threads (4 waves), 16 rows/block -> 4 blk/CU.
// Phase 1: x staged CONTIGUOUSLY to LDS via global_load_lds (1 KB per row per
// K-step of 256), intra-row XOR swizzle (block^(row&7)) for conflict-free
// fragment ds_reads. 16 steps, double-buffered, 1 barrier/step. Waves split
// the 8 k-subchunks (2 each); partials reduced in reused LDS.
// Phase 2: out = h @ Bpack with SWAPPED mfma operands -> lane holds 4
// consecutive out-cols -> single dwordx4 store per tile. Weights L2-resident.
// ---------------------------------------------------------------------------
__global__ __launch_bounds__(256, 4) void lora_fused(
    const float* __restrict__ x, const short* __restrict__ Apack,
    const short* __restrict__ Bpack, float* __restrict__ out)
{
  const int rb  = blockIdx.x;            // 16-row tile
  const int tid = threadIdx.x;
  const int w = tid >> 6, l = tid & 63;
  const int lm = l & 15, lk = l >> 4;
  const size_t rowbase = (size_t)rb * 16;

  __shared__ __align__(16) float smem[8192];   // 32 KiB: xs dbuf, then hp+hfrag

  // ---- phase 1 ----
  // stage step s into buffer b: wave w covers rows w*4..w*4+3, one 1-KB
  // instruction per row; lane j's source block = j ^ (r&7) (contiguous union)
  auto stage = [&](int s, int b) {
    float* base = smem + b * 4096;
    const float* gx = x + rowbase * 4096 + s * 256;
#pragma unroll
    for (int i = 0; i < 4; ++i) {
      int r = w * 4 + i;
      const float* gp = gx + (size_t)r * 4096 + ((l ^ (r & 7)) << 2);
      async_ld16(gp, base + r * 256);
    }
  };

  f32x4 acc[6];
#pragma unroll
  for (int t = 0; t < 6; ++t) acc[t] = (f32x4){0.f, 0.f, 0.f, 0.f};

  stage(0, 0);
  for (int st = 0; st < 16; ++st) {
    __syncthreads();                      // buf[st&1] staged; prior reads done
    if (st < 15) stage(st + 1, (st + 1) & 1);
    const float* buf = smem + (st & 1) * 4096;
    const float* rowp = buf + lm * 256;
    const int sw = lm & 7;
#pragma unroll
    for (int p = 0; p < 2; ++p) {
      int ksub = w * 2 + p;
      int b0 = ksub * 8 + lk * 2;         // 16-B block index in row chunk
      f32x4 xa = *(const f32x4*)(rowp + (((b0)     ^ sw) << 2));
      f32x4 xb = *(const f32x4*)(rowp + (((b0 + 1) ^ sw) << 2));
      bf16x8 xf;
      xf[0] = (short)f2bf(xa[0]); xf[1] = (short)f2bf(xa[1]);
      xf[2] = (short)f2bf(xa[2]); xf[3] = (short)f2bf(xa[3]);
      xf[4] = (short)f2bf(xb[0]); xf[5] = (short)f2bf(xb[1]);
      xf[6] = (short)f2bf(xb[2]); xf[7] = (short)f2bf(xb[3]);
      int kchunk = st * 8 + ksub;         // global 32-k chunk 0..127
#pragma unroll
      for (int t = 0; t < 6; ++t) {
        bf16x8 av = *(const bf16x8*)(Apack + ((size_t)kchunk * 6 + t) * 512 + l * 8);
        acc[t] = __builtin_amdgcn_mfma_f32_16x16x32_bf16(xf, av, acc[t], 0, 0, 0);
      }
    }
  }
  __syncthreads();                        // xs reads done; reuse smem

  // partials: lane holds h_part[row=lk*4+q][col=t*16+lm]; wave w -> hp slot w
  {
    float* hpw = smem + w * 1600;         // [16][100] padded
#pragma unroll
    for (int t = 0; t < 6; ++t)
#pragma unroll
      for (int q = 0; q < 4; ++q)
        hpw[(lk * 4 + q) * 100 + t * 16 + lm] = acc[t][q];
  }
  __syncthreads();

  // reduce 4 partials -> bf16 B-op fragments: hfrag[kc][lane][j]
  if (tid < 192) {
    int r = tid / 12, c8 = tid % 12;      // row 0..15, col-group of 8
    const float* p = smem + r * 100 + c8 * 8;
    f32x4 s0 = *(const f32x4*)(p)     + *(const f32x4*)(p + 1600)
             + *(const f32x4*)(p + 3200) + *(const f32x4*)(p + 4800);
    f32x4 s1 = *(const f32x4*)(p + 4) + *(const f32x4*)(p + 1604)
             + *(const f32x4*)(p + 3204) + *(const f32x4*)(p + 4804);
    bf16x8 o;
    o[0] = (short)f2bf(s0[0]); o[1] = (short)f2bf(s0[1]);
    o[2] = (short)f2bf(s0[2]); o[3] = (short)f2bf(s0[3]);
    o[4] = (short)f2bf(s1[0]); o[5] = (short)f2bf(s1[1]);
    o[6] = (short)f2bf(s1[2]); o[7] = (short)f2bf(s1[3]);
    short* hfr = (short*)(smem + 6400);
    *(bf16x8*)(hfr + ((c8 >> 2) * 64 + (c8 & 3) * 16 + r) * 8) = o;
  }
  __syncthreads();

  // ---- phase 2: out[16][4096] = h @ Bpack, swapped operands ----
  {
    const short* hfr = (const short*)(smem + 6400);
    bf16x8 hf[3];
#pragma unroll
    for (int kc = 0; kc < 3; ++kc)
      hf[kc] = *(const bf16x8*)(hfr + (kc * 64 + l) * 8);   // lane-linear

    float* orow = out + (rowbase + lm) * 4096;
#pragma unroll 4
    for (int i = 0; i < 64; ++i) {
      int nt = w * 64 + i;                // n-tile 0..255
      f32x4 a = {0.f, 0.f, 0.f, 0.f};
#pragma unroll
      for (int kc = 0; kc < 3; ++kc) {
        bf16x8 bv = *(const bf16x8*)(Bpack + ((size_t)(kc * 256 + nt)) * 512 + l * 8);
        // D[mcol][nrow]: lane -> row=lane&15, cols=(lane>>4)*4+q
        a = __builtin_amdgcn_mfma_f32_16x16x32_bf16(bv, hf[kc], a, 0, 0, 0);
      }
      *(f32x4*)(orow + nt * 16 + lk * 4) = a;
    }
  }
}

extern "C" void kernel_launch(void* const* d_in, const int* in_sizes, int n_in,
                              void* d_out, int out_size, void* d_ws, size_t ws_size,
                              hipStream_t stream) {
  const float* x  = (const float*)d_in[0];
  const float* Af = (const float*)d_in[1];
  const float* Bf = (const float*)d_in[2];
  const float* Am = (const float*)d_in[3];
  const float* Bm = (const float*)d_in[4];
  const float* As = (const float*)d_in[5];
  const float* Bs = (const float*)d_in[6];
  float* out = (float*)d_out;

  char* ws = (char*)d_ws;
  short* Apack = (short*)ws;                  // 786432 B
  short* Bpack = (short*)(ws + 786432);       // 786432 B

  hipLaunchKernelGGL(pack_AB, dim3(3072), dim3(256), 0, stream,
                     Af, Am, As, Bf, Bm, Bs, Apack, Bpack);
  hipLaunchKernelGGL(lora_fused, dim3(1024), dim3(256), 0, stream, x, Apack, Bpack, out);
}

// Round 7
// 155.597 us; speedup vs baseline: 1.2522x; 1.1138x over previous
//
#include <hip/hip_runtime.h>
#include <hip/hip_bf16.h>

typedef __attribute__((ext_vector_type(4))) float f32x4;
typedef __attribute__((ext_vector_type(8))) short bf16x8;

// fp32 -> bf16 bits, round-to-nearest-even
__device__ __forceinline__ unsigned short f2bf(float f) {
  unsigned int u = __builtin_bit_cast(unsigned int, f);
  u += 0x7FFFu + ((u >> 16) & 1u);
  return (unsigned short)(u >> 16);
}

// async 16B global -> LDS (wave-uniform LDS base + lane*16 hardware layout)
__device__ __forceinline__ void async_ld16(const void* g, void* l) {
  __builtin_amdgcn_global_load_lds(
      (__attribute__((address_space(1))) void*)g,
      (__attribute__((address_space(3))) void*)l, 16, 0, 0);
}

// ---------------------------------------------------------------------------
// Weight packing: fragment-order bf16 (same lane-mapping serves A-op & B-op).
// Apack[chunk][t][lane][j] = Acat[chunk*32 + (lane>>4)*8 + j][t*16 + (lane&15)]
// Bpack[kc][nt][lane][j]   = SCALE * Bcat[kc*32 + (lane>>4)*8 + j][nt*16 + (lane&15)]
// ---------------------------------------------------------------------------
__global__ __launch_bounds__(256) void pack_AB(
    const float* __restrict__ Af, const float* __restrict__ Am,
    const float* __restrict__ As, const float* __restrict__ Bf,
    const float* __restrict__ Bm, const float* __restrict__ Bs,
    short* __restrict__ Apack, short* __restrict__ Bpack)
{
  unsigned idx = blockIdx.x * 256u + threadIdx.x;     // < 786432
  if (idx < 393216u) {
    unsigned j = idx & 7u, lane = (idx >> 3) & 63u, rest = idx >> 9;
    unsigned t = rest % 6u, chunk = rest / 6u;
    unsigned k = chunk * 32u + ((lane >> 4) << 3) + j;
    unsigned c = t * 16u + (lane & 15u);
    float v;
    if (c < 32u)      v = Af[k * 32u + c];
    else if (c < 64u) v = Am[k * 32u + (c - 32u)];
    else              v = As[k * 32u + (c - 64u)];
    Apack[idx] = (short)f2bf(v);
  } else {
    unsigned i2 = idx - 393216u;
    unsigned j = i2 & 7u, lane = (i2 >> 3) & 63u, rest = i2 >> 9;
    unsigned nt = rest & 255u, kc = rest >> 8;
    unsigned k = kc * 32u + ((lane >> 4) << 3) + j;
    unsigned n = nt * 16u + (lane & 15u);
    float v;
    if (k < 32u)      v = Bf[k * 4096u + n];
    else if (k < 64u) v = Bm[(k - 32u) * 4096u + n];
    else              v = Bs[(k - 64u) * 4096u + n];
    Bpack[i2] = (short)f2bf(v * 0.03125f);            // fold SCALE = 1/32
  }
}

// ---------------------------------------------------------------------------
// Stage 1: hg fragments = x @ Apack. 1024 blocks (16 rows) x 4 waves.
// Contiguous gload_lds staging (1 KB/row/step, XOR-swizzled source), DOUBLE
// buffer with RAW s_barrier + counted s_waitcnt vmcnt(4) -- never drains the
// in-flight prefetch (T4). Partials reduced in reused LDS -> bf16 fragments
// to global hg (3 KB/tile).
// ---------------------------------------------------------------------------
__global__ __launch_bounds__(256, 4) void lora_stage1(
    const float* __restrict__ x, const short* __restrict__ Apack,
    short* __restrict__ hg)
{
  const int rb  = blockIdx.x;            // 16-row tile
  const int tid = threadIdx.x;
  const int w = tid >> 6, l = tid & 63;
  const int lm = l & 15, lk = l >> 4;
  const size_t rowbase = (size_t)rb * 16;

  __shared__ __align__(16) float smem[8192];   // 32 KiB: xs dbuf -> hp reuse

  f32x4 acc[6];
#pragma unroll
  for (int t = 0; t < 6; ++t) acc[t] = (f32x4){0.f, 0.f, 0.f, 0.f};

  // stage step s into buffer b: wave w rows w*4..+3, 1 KB contiguous per row,
  // per-lane source block = l ^ (r&7) (bank-spread on fragment reads)
  auto stage = [&](int s, int b) {
    float* base = smem + b * 4096;
    const float* gx = x + rowbase * 4096 + s * 256;
#pragma unroll
    for (int i = 0; i < 4; ++i) {
      int r = w * 4 + i;
      async_ld16(gx + (size_t)r * 4096 + ((l ^ (r & 7)) << 2), base + r * 256);
    }
  };

  auto consume = [&](int st) {
    const float* rowp = smem + (st & 1) * 4096 + lm * 256;
    const int sw = lm & 7;
#pragma unroll
    for (int p = 0; p < 2; ++p) {
      int ksub = w * 2 + p;
      int b0 = ksub * 8 + lk * 2;
      f32x4 xa = *(const f32x4*)(rowp + (((b0)     ^ sw) << 2));
      f32x4 xb = *(const f32x4*)(rowp + (((b0 + 1) ^ sw) << 2));
      bf16x8 xf;
      xf[0] = (short)f2bf(xa[0]); xf[1] = (short)f2bf(xa[1]);
      xf[2] = (short)f2bf(xa[2]); xf[3] = (short)f2bf(xa[3]);
      xf[4] = (short)f2bf(xb[0]); xf[5] = (short)f2bf(xb[1]);
      xf[6] = (short)f2bf(xb[2]); xf[7] = (short)f2bf(xb[3]);
      int kchunk = st * 8 + ksub;
#pragma unroll
      for (int t = 0; t < 6; ++t) {
        bf16x8 av = *(const bf16x8*)(Apack + ((size_t)kchunk * 6 + t) * 512 + l * 8);
        acc[t] = __builtin_amdgcn_mfma_f32_16x16x32_bf16(xf, av, acc[t], 0, 0, 0);
      }
    }
  };

  stage(0, 0);
#pragma unroll 1
  for (int st = 0; st < 15; ++st) {
    stage(st + 1, (st + 1) & 1);         // issue next step FIRST (FIFO shape)
    __builtin_amdgcn_sched_barrier(0);
    asm volatile("s_waitcnt vmcnt(4)" ::: "memory");   // oldest step landed
    __builtin_amdgcn_sched_barrier(0);
    __builtin_amdgcn_s_barrier();        // raw barrier: NO vmcnt(0) drain
    __builtin_amdgcn_sched_barrier(0);
    consume(st);
    __builtin_amdgcn_sched_barrier(0);
    __builtin_amdgcn_s_barrier();        // reads done before buf reuse
    __builtin_amdgcn_sched_barrier(0);
  }
  asm volatile("s_waitcnt vmcnt(0)" ::: "memory");
  __builtin_amdgcn_sched_barrier(0);
  __builtin_amdgcn_s_barrier();
  __builtin_amdgcn_sched_barrier(0);
  consume(15);
  __syncthreads();                       // full drain before smem reuse

  // partials: hp[w][16][100] in reused smem
  {
    float* hpw = smem + w * 1600;
#pragma unroll
    for (int t = 0; t < 6; ++t)
#pragma unroll
      for (int q = 0; q < 4; ++q)
        hpw[(lk * 4 + q) * 100 + t * 16 + lm] = acc[t][q];
  }
  __syncthreads();

  // reduce 4 wave-partials -> bf16 fragments -> global hg[tile][kc][lane][8]
  if (tid < 192) {
    int r = tid / 12, c8 = tid % 12;     // row 0..15, col-group of 8
    const float* p = smem + r * 100 + c8 * 8;
    f32x4 s0 = *(const f32x4*)(p)        + *(const f32x4*)(p + 1600)
             + *(const f32x4*)(p + 3200) + *(const f32x4*)(p + 4800);
    f32x4 s1 = *(const f32x4*)(p + 4)    + *(const f32x4*)(p + 1604)
             + *(const f32x4*)(p + 3204) + *(const f32x4*)(p + 4804);
    bf16x8 o;
    o[0] = (short)f2bf(s0[0]); o[1] = (short)f2bf(s0[1]);
    o[2] = (short)f2bf(s0[2]); o[3] = (short)f2bf(s0[3]);
    o[4] = (short)f2bf(s1[0]); o[5] = (short)f2bf(s1[1]);
    o[6] = (short)f2bf(s1[2]); o[7] = (short)f2bf(s1[3]);
    *(bf16x8*)(hg + ((size_t)rb * 192 + (c8 >> 2) * 64 + (c8 & 3) * 16 + r) * 8) = o;
  }
}

// ---------------------------------------------------------------------------
// Stage 2: out = h @ Bpack. 2048 blocks (64 rows x 512 cols) x 4 waves, no
// LDS -> up to 8 blocks/CU (32 waves) of TLP to hide L2 latency. Swapped
// mfma operands (round-6-verified): lane stores one contiguous dwordx4.
// ---------------------------------------------------------------------------
__global__ __launch_bounds__(256, 8) void lora_stage2(
    const short* __restrict__ hg, const short* __restrict__ Bpack,
    float* __restrict__ out)
{
  const int rb = blockIdx.x >> 3;        // 64-row group
  const int cb = blockIdx.x & 7;         // 512-col group
  const int tid = threadIdx.x;
  const int w = tid >> 6, l = tid & 63;
  const int lm = l & 15, lk = l >> 4;
  const int tile = rb * 4 + w;           // this wave's 16-row tile

  bf16x8 hf[3];
#pragma unroll
  for (int kc = 0; kc < 3; ++kc)
    hf[kc] = *(const bf16x8*)(hg + ((size_t)tile * 192 + kc * 64 + l) * 8);

  float* orow = out + ((size_t)tile * 16 + lm) * 4096;
  const short* bp = Bpack + (size_t)l * 8;

#pragma unroll 2
  for (int i = 0; i < 32; ++i) {
    int nt = cb * 32 + i;                // n-tile 0..255
    f32x4 a = {0.f, 0.f, 0.f, 0.f};
#pragma unroll
    for (int kc = 0; kc < 3; ++kc) {
      bf16x8 bv = *(const bf16x8*)(bp + (size_t)(kc * 256 + nt) * 512);
      a = __builtin_amdgcn_mfma_f32_16x16x32_bf16(bv, hf[kc], a, 0, 0, 0);
    }
    *(f32x4*)(orow + nt * 16 + lk * 4) = a;
  }
}

extern "C" void kernel_launch(void* const* d_in, const int* in_sizes, int n_in,
                              void* d_out, int out_size, void* d_ws, size_t ws_size,
                              hipStream_t stream) {
  const float* x  = (const float*)d_in[0];
  const float* Af = (const float*)d_in[1];
  const float* Bf = (const float*)d_in[2];
  const float* Am = (const float*)d_in[3];
  const float* Bm = (const float*)d_in[4];
  const float* As = (const float*)d_in[5];
  const float* Bs = (const float*)d_in[6];
  float* out = (float*)d_out;

  char* ws = (char*)d_ws;
  short* Apack = (short*)ws;                    // 786432 B
  short* Bpack = (short*)(ws + 786432);         // 786432 B
  short* hg    = (short*)(ws + 2 * 786432);     // 1024*192*8*2 = 3145728 B

  hipLaunchKernelGGL(pack_AB, dim3(3072), dim3(256), 0, stream,
                     Af, Am, As, Bf, Bm, Bs, Apack, Bpack);
  hipLaunchKernelGGL(lora_stage1, dim3(1024), dim3(256), 0, stream, x, Apack, hg);
  hipLaunchKernelGGL(lora_stage2, dim3(2048), dim3(256), 0, stream, hg, Bpack, out);
}

// Round 8
// 141.420 us; speedup vs baseline: 1.3777x; 1.1003x over previous
//
#include <hip/hip_runtime.h>
#include <hip/hip_bf16.h>

typedef __attribute__((ext_vector_type(4))) float f32x4;
typedef __attribute__((ext_vector_type(8))) short bf16x8;

// fp32 -> bf16 bits, round-to-nearest-even
__device__ __forceinline__ unsigned short f2bf(float f) {
  unsigned int u = __builtin_bit_cast(unsigned int, f);
  u += 0x7FFFu + ((u >> 16) & 1u);
  return (unsigned short)(u >> 16);
}

// async 16B global -> LDS (wave-uniform LDS base + lane*16 hardware layout)
__device__ __forceinline__ void async_ld16(const void* g, void* l) {
  __builtin_amdgcn_global_load_lds(
      (__attribute__((address_space(1))) void*)g,
      (__attribute__((address_space(3))) void*)l, 16, 0, 0);
}

// ---------------------------------------------------------------------------
// Weight packing: fragment-order bf16 (same lane-mapping serves A-op & B-op).
// Apack[chunk][t][lane][j] = Acat[chunk*32 + (lane>>4)*8 + j][t*16 + (lane&15)]
// Bpack[kc][nt][lane][j]   = SCALE * Bcat[kc*32 + (lane>>4)*8 + j][nt*16 + (lane&15)]
// ---------------------------------------------------------------------------
__global__ __launch_bounds__(256) void pack_AB(
    const float* __restrict__ Af, const float* __restrict__ Am,
    const float* __restrict__ As, const float* __restrict__ Bf,
    const float* __restrict__ Bm, const float* __restrict__ Bs,
    short* __restrict__ Apack, short* __restrict__ Bpack)
{
  unsigned idx = blockIdx.x * 256u + threadIdx.x;     // < 786432
  if (idx < 393216u) {
    unsigned j = idx & 7u, lane = (idx >> 3) & 63u, rest = idx >> 9;
    unsigned t = rest % 6u, chunk = rest / 6u;
    unsigned k = chunk * 32u + ((lane >> 4) << 3) + j;
    unsigned c = t * 16u + (lane & 15u);
    float v;
    if (c < 32u)      v = Af[k * 32u + c];
    else if (c < 64u) v = Am[k * 32u + (c - 32u)];
    else              v = As[k * 32u + (c - 64u)];
    Apack[idx] = (short)f2bf(v);
  } else {
    unsigned i2 = idx - 393216u;
    unsigned j = i2 & 7u, lane = (i2 >> 3) & 63u, rest = i2 >> 9;
    unsigned nt = rest & 255u, kc = rest >> 8;
    unsigned k = kc * 32u + ((lane >> 4) << 3) + j;
    unsigned n = nt * 16u + (lane & 15u);
    float v;
    if (k < 32u)      v = Bf[k * 4096u + n];
    else if (k < 64u) v = Bm[(k - 32u) * 4096u + n];
    else              v = Bs[(k - 64u) * 4096u + n];
    Bpack[i2] = (short)f2bf(v * 0.03125f);            // fold SCALE = 1/32
  }
}

// ---------------------------------------------------------------------------
// Stage 1 (unchanged from round 7 -- proven): hg fragments = x @ Apack.
// 1024 blocks (16 rows) x 4 waves. Contiguous gload_lds staging, double
// buffer with RAW s_barrier + counted s_waitcnt vmcnt(4).
// ---------------------------------------------------------------------------
__global__ __launch_bounds__(256, 4) void lora_stage1(
    const float* __restrict__ x, const short* __restrict__ Apack,
    short* __restrict__ hg)
{
  const int rb  = blockIdx.x;            // 16-row tile
  const int tid = threadIdx.x;
  const int w = tid >> 6, l = tid & 63;
  const int lm = l & 15, lk = l >> 4;
  const size_t rowbase = (size_t)rb * 16;

  __shared__ __align__(16) float smem[8192];   // 32 KiB: xs dbuf -> hp reuse

  f32x4 acc[6];
#pragma unroll
  for (int t = 0; t < 6; ++t) acc[t] = (f32x4){0.f, 0.f, 0.f, 0.f};

  auto stage = [&](int s, int b) {
    float* base = smem + b * 4096;
    const float* gx = x + rowbase * 4096 + s * 256;
#pragma unroll
    for (int i = 0; i < 4; ++i) {
      int r = w * 4 + i;
      async_ld16(gx + (size_t)r * 4096 + ((l ^ (r & 7)) << 2), base + r * 256);
    }
  };

  auto consume = [&](int st) {
    const float* rowp = smem + (st & 1) * 4096 + lm * 256;
    const int sw = lm & 7;
#pragma unroll
    for (int p = 0; p < 2; ++p) {
      int ksub = w * 2 + p;
      int b0 = ksub * 8 + lk * 2;
      f32x4 xa = *(const f32x4*)(rowp + (((b0)     ^ sw) << 2));
      f32x4 xb = *(const f32x4*)(rowp + (((b0 + 1) ^ sw) << 2));
      bf16x8 xf;
      xf[0] = (short)f2bf(xa[0]); xf[1] = (short)f2bf(xa[1]);
      xf[2] = (short)f2bf(xa[2]); xf[3] = (short)f2bf(xa[3]);
      xf[4] = (short)f2bf(xb[0]); xf[5] = (short)f2bf(xb[1]);
      xf[6] = (short)f2bf(xb[2]); xf[7] = (short)f2bf(xb[3]);
      int kchunk = st * 8 + ksub;
#pragma unroll
      for (int t = 0; t < 6; ++t) {
        bf16x8 av = *(const bf16x8*)(Apack + ((size_t)kchunk * 6 + t) * 512 + l * 8);
        acc[t] = __builtin_amdgcn_mfma_f32_16x16x32_bf16(xf, av, acc[t], 0, 0, 0);
      }
    }
  };

  stage(0, 0);
#pragma unroll 1
  for (int st = 0; st < 15; ++st) {
    stage(st + 1, (st + 1) & 1);         // issue next step FIRST (FIFO shape)
    __builtin_amdgcn_sched_barrier(0);
    asm volatile("s_waitcnt vmcnt(4)" ::: "memory");   // oldest step landed
    __builtin_amdgcn_sched_barrier(0);
    __builtin_amdgcn_s_barrier();        // raw barrier: NO vmcnt(0) drain
    __builtin_amdgcn_sched_barrier(0);
    consume(st);
    __builtin_amdgcn_sched_barrier(0);
    __builtin_amdgcn_s_barrier();        // reads done before buf reuse
    __builtin_amdgcn_sched_barrier(0);
  }
  asm volatile("s_waitcnt vmcnt(0)" ::: "memory");
  __builtin_amdgcn_sched_barrier(0);
  __builtin_amdgcn_s_barrier();
  __builtin_amdgcn_sched_barrier(0);
  consume(15);
  __syncthreads();                       // full drain before smem reuse

  // partials: hp[w][16][100] in reused smem
  {
    float* hpw = smem + w * 1600;
#pragma unroll
    for (int t = 0; t < 6; ++t)
#pragma unroll
      for (int q = 0; q < 4; ++q)
        hpw[(lk * 4 + q) * 100 + t * 16 + lm] = acc[t][q];
  }
  __syncthreads();

  // reduce 4 wave-partials -> bf16 fragments -> global hg[tile][kc][lane][8]
  if (tid < 192) {
    int r = tid / 12, c8 = tid % 12;     // row 0..15, col-group of 8
    const float* p = smem + r * 100 + c8 * 8;
    f32x4 s0 = *(const f32x4*)(p)        + *(const f32x4*)(p + 1600)
             + *(const f32x4*)(p + 3200) + *(const f32x4*)(p + 4800);
    f32x4 s1 = *(const f32x4*)(p + 4)    + *(const f32x4*)(p + 1604)
             + *(const f32x4*)(p + 3204) + *(const f32x4*)(p + 4804);
    bf16x8 o;
    o[0] = (short)f2bf(s0[0]); o[1] = (short)f2bf(s0[1]);
    o[2] = (short)f2bf(s0[2]); o[3] = (short)f2bf(s0[3]);
    o[4] = (short)f2bf(s1[0]); o[5] = (short)f2bf(s1[1]);
    o[6] = (short)f2bf(s1[2]); o[7] = (short)f2bf(s1[3]);
    *(bf16x8*)(hg + ((size_t)rb * 192 + (c8 >> 2) * 64 + (c8 & 3) * 16 + r) * 8) = o;
  }
}

// ---------------------------------------------------------------------------
// Stage 2 (REDESIGNED): B-fragments RESIDENT in registers, iterate over rows.
// 2048 blocks = 128 row-slabs (8 tiles) x 16 col-groups (256 cols); 4 waves,
// each owning 4 n-tiles (12 persistent B-frags = 48 VGPR). Per iter: 3 tiny
// hg loads (L1/L2-hit, shared by all 4 waves) + 12 MFMA + 4 dwordx4 stores.
// Bpack L2 traffic drops 8x (786->98 MB) -> HBM-write-bound (~42 us floor).
// ---------------------------------------------------------------------------
__global__ __launch_bounds__(256, 4) void lora_stage2(
    const short* __restrict__ hg, const short* __restrict__ Bpack,
    float* __restrict__ out)
{
  const int bid = blockIdx.x;
  const int rs = bid >> 4;               // row-slab: tiles rs*8 .. +8
  const int cb = bid & 15;               // 256-col group
  const int tid = threadIdx.x;
  const int w = tid >> 6, l = tid & 63;
  const int lm = l & 15, lk = l >> 4;
  const int nt0 = cb * 16 + w * 4;       // wave's 4 n-tiles

  // persistent B fragments: 4 nt x 3 kc (48 VGPR)
  bf16x8 bf[4][3];
#pragma unroll
  for (int n = 0; n < 4; ++n)
#pragma unroll
    for (int kc = 0; kc < 3; ++kc)
      bf[n][kc] = *(const bf16x8*)(Bpack + ((size_t)(kc * 256 + nt0 + n)) * 512 + l * 8);

#pragma unroll 2
  for (int it = 0; it < 8; ++it) {
    const int tile = rs * 8 + it;
    const short* hp = hg + (size_t)tile * 1536 + (size_t)l * 8;  // 192*8 shorts/tile
    bf16x8 hf0 = *(const bf16x8*)(hp);
    bf16x8 hf1 = *(const bf16x8*)(hp + 512);
    bf16x8 hf2 = *(const bf16x8*)(hp + 1024);
    float* orow = out + ((size_t)tile * 16 + lm) * 4096;
#pragma unroll
    for (int n = 0; n < 4; ++n) {
      f32x4 a = {0.f, 0.f, 0.f, 0.f};
      a = __builtin_amdgcn_mfma_f32_16x16x32_bf16(bf[n][0], hf0, a, 0, 0, 0);
      a = __builtin_amdgcn_mfma_f32_16x16x32_bf16(bf[n][1], hf1, a, 0, 0, 0);
      a = __builtin_amdgcn_mfma_f32_16x16x32_bf16(bf[n][2], hf2, a, 0, 0, 0);
      *(f32x4*)(orow + (nt0 + n) * 16 + lk * 4) = a;
    }
  }
}

extern "C" void kernel_launch(void* const* d_in, const int* in_sizes, int n_in,
                              void* d_out, int out_size, void* d_ws, size_t ws_size,
                              hipStream_t stream) {
  const float* x  = (const float*)d_in[0];
  const float* Af = (const float*)d_in[1];
  const float* Bf = (const float*)d_in[2];
  const float* Am = (const float*)d_in[3];
  const float* Bm = (const float*)d_in[4];
  const float* As = (const float*)d_in[5];
  const float* Bs = (const float*)d_in[6];
  float* out = (float*)d_out;

  char* ws = (char*)d_ws;
  short* Apack = (short*)ws;                    // 786432 B
  short* Bpack = (short*)(ws + 786432);         // 786432 B
  short* hg    = (short*)(ws + 2 * 786432);     // 1024*192*8*2 = 3145728 B

  hipLaunchKernelGGL(pack_AB, dim3(3072), dim3(256), 0, stream,
                     Af, Am, As, Bf, Bm, Bs, Apack, Bpack);
  hipLaunchKernelGGL(lora_stage1, dim3(1024), dim3(256), 0, stream, x, Apack, hg);
  hipLaunchKernelGGL(lora_stage2, dim3(2048), dim3(256), 0, stream, hg, Bpack, out);
}